// Round 15
// baseline (49.509 us; speedup 1.0000x reference)
//
#include <hip/hip_runtime.h>
#include <hip/hip_bf16.h>

// Self-attention: b=32, s=2048, d=32, f32 in/out.
// qkv (split, 3-head grid): x tile staged COALESCED into padded LDS (new);
//   Q pre-scaled by log2e/sqrt(32); K fragment-order (KF); V fragment-order (VF).
// attn: BYTE-IDENTICAL to round-12 pass (double-buffered LDS reg-staging,
//   compute -> barrier -> ds_write -> barrier, compiler-managed waits only).
// ws: KF 4MB | VF 4MB | Qb 4MB.

typedef __attribute__((ext_vector_type(8))) short bf16x8;
typedef __attribute__((ext_vector_type(4))) short bf16x4;
typedef __attribute__((ext_vector_type(4))) float f32x4;
typedef __attribute__((ext_vector_type(2))) unsigned int u32x2;
typedef __attribute__((ext_vector_type(4))) unsigned int u32x4;

#if __has_builtin(__builtin_amdgcn_mfma_f32_16x16x16bf16_1k)
#define MFMA_PV(a, b, c) __builtin_amdgcn_mfma_f32_16x16x16bf16_1k(a, b, c, 0, 0, 0)
#elif defined(__HIP_DEVICE_COMPILE__)
#error "no 16x16x16 bf16 mfma builtin on device"
#else
#define MFMA_PV(a, b, c) (c) /* host stub, never executed */
#endif

__device__ __forceinline__ unsigned cvt_pk_bf16(float lo, float hi) {
  unsigned r;
  asm("v_cvt_pk_bf16_f32 %0, %1, %2" : "=v"(r) : "v"(lo), "v"(hi));
  return r;
}
__device__ __forceinline__ bf16x4 as_bf16x4(u32x2 u) {
  union { u32x2 a; bf16x4 b; } c; c.a = u; return c.b;
}

// ---------------- QKV projection (coalesced x staging; repack paths R12-verified) ----
// grid 1536 = 3 heads x 512 blocks; 256 thr; half = tid>>7, 128 rows/block
__global__ __launch_bounds__(256) void qkv_kernel(
    const float* __restrict__ x, const float* __restrict__ w,
    unsigned short* __restrict__ Qb, unsigned short* __restrict__ KF,
    unsigned short* __restrict__ VF) {
  __shared__ float Wlds[1024];
  __shared__ float xs[4608];                       // 128 rows x 36 floats (pad +4)
  __shared__ __align__(16) unsigned char RP[8192]; // repack buffer (h==1 / h==2)
  int tid = threadIdx.x;
  int h = blockIdx.x >> 9;
  int rb = blockIdx.x & 511;

  // coalesced x tile stage: 16KB = 256 thr x 4 x f32x4; padded rows (144B, 16B-aligned)
  const float* xg = x + (size_t)(rb * 128) * 32;
#pragma unroll
  for (int k2 = 0; k2 < 4; ++k2) {
    int fi = k2 * 1024 + tid * 4;
    f32x4 v = *(const f32x4*)(xg + fi);
    *(f32x4*)(&xs[(fi >> 5) * 36 + (fi & 31)]) = v;
  }
#pragma unroll
  for (int i = 0; i < 4; ++i) Wlds[i * 256 + tid] = w[h * 1024 + i * 256 + tid];
  __syncthreads();

  int half = tid >> 7;
  int row = rb * 128 + (tid & 127);
  const float* xr = &xs[(tid & 127) * 36];
  f32x4 xv[8];
#pragma unroll
  for (int j = 0; j < 8; ++j) xv[j] = *(const f32x4*)(xr + j * 4);

  f32x4 acc[4];
#pragma unroll
  for (int j = 0; j < 4; ++j) acc[j] = (f32x4)0.0f;
#pragma unroll
  for (int d = 0; d < 32; ++d) {
    float xd = xv[d >> 2][d & 3];
    const f32x4* wr = (const f32x4*)&Wlds[d * 32 + half * 16];
#pragma unroll
    for (int j = 0; j < 4; ++j) acc[j] += xd * wr[j];
  }

  const float alpha = 1.4426950408889634f * 0.17677669529663687f; // log2e/sqrt(32)
  int L = tid & 127;

  if (h == 0) {
    u32x4 o4[2];
#pragma unroll
    for (int q = 0; q < 2; ++q)
#pragma unroll
      for (int c = 0; c < 4; ++c) {
        int e = q * 8 + c * 2;
        o4[q][c] = cvt_pk_bf16(acc[e >> 2][e & 3] * alpha, acc[(e + 1) >> 2][(e + 1) & 3] * alpha);
      }
    u32x4* dst = (u32x4*)(Qb + (size_t)row * 32 + half * 16);
    dst[0] = o4[0];
    dst[1] = o4[1];
  } else if (h == 1) {
    // K fragment-order: tile byte = kt*1024 + g*256 + n*16 (+ kcl*4096)  [R12-verified]
    int kcl = L >> 6, kt = (L >> 4) & 3, n = L & 15;
    u32x4 o4[2];
#pragma unroll
    for (int q = 0; q < 2; ++q)
#pragma unroll
      for (int c = 0; c < 4; ++c) {
        int e = q * 8 + c * 2;
        o4[q][c] = cvt_pk_bf16(acc[e >> 2][e & 3], acc[(e + 1) >> 2][(e + 1) & 3]);
      }
    *(u32x4*)(RP + kcl * 4096 + kt * 1024 + (2 * half + 0) * 256 + n * 16) = o4[0];
    *(u32x4*)(RP + kcl * 4096 + kt * 1024 + (2 * half + 1) * 256 + n * 16) = o4[1];
    __syncthreads();
    char* dst = (char*)KF + (size_t)rb * 8192;
#pragma unroll
    for (int m = 0; m < 4; ++m)
      *(u32x2*)(dst + tid * 8 + m * 2048) = *(const u32x2*)(RP + tid * 8 + m * 2048);
  } else {
    // V fragment-order repack (verified rounds 6/9/12)
    unsigned short* VFlds = (unsigned short*)RP;
    int kcl = L >> 6, kt = (L >> 4) & 3, g = (L >> 2) & 3, i = L & 3;
    int base = kcl * 2048 + half * 1024 + kt * 256 + g * 64 + i;
#pragma unroll
    for (int nn = 0; nn < 16; ++nn) {
      unsigned r = cvt_pk_bf16(acc[nn >> 2][nn & 3], acc[nn >> 2][nn & 3]);
      VFlds[base + nn * 4] = (unsigned short)(r & 0xffffu);
    }
    __syncthreads();
    char* dst = (char*)VF + (size_t)rb * 8192;
#pragma unroll
    for (int m = 0; m < 4; ++m)
      *(u32x2*)(dst + tid * 8 + m * 2048) = *(const u32x2*)(RP + tid * 8 + m * 2048);
  }
}

// ---------------- Flash attention (BYTE-IDENTICAL to round-12 pass) ----------------
#define SMAX(SF, I2) {                                           \
    float p0 = __builtin_amdgcn_exp2f(SF[0]);                    \
    float p1 = __builtin_amdgcn_exp2f(SF[1]);                    \
    float p2 = __builtin_amdgcn_exp2f(SF[2]);                    \
    float p3 = __builtin_amdgcn_exp2f(SF[3]);                    \
    lsum += (p0 + p1) + (p2 + p3);                               \
    pk[I2] = cvt_pk_bf16(p0, p1);                                \
    pk[I2 + 1] = cvt_pk_bf16(p2, p3); }

#define PVKT(KT, V0, V1, ACC0, ACC1) {                           \
    u32x2 bw; bw[0] = pk[2 * KT]; bw[1] = pk[2 * KT + 1];        \
    bf16x4 bb = as_bf16x4(bw);                                   \
    ACC0 = MFMA_PV(as_bf16x4(V0), bb, ACC0);                     \
    ACC1 = MFMA_PV(as_bf16x4(V1), bb, ACC1); }

// grid: 1024 blocks (32 b x 32 q-tiles of 64), 256 threads (4 waves x 16 q-rows)
__global__ __launch_bounds__(256, 4) void attn_kernel(
    const unsigned short* __restrict__ Qb, const unsigned short* __restrict__ KF,
    const unsigned short* __restrict__ VF, float* __restrict__ out) {
  __shared__ __align__(16) unsigned char lds[2][8192]; // 2 x (K 4KB | V 4KB)
  unsigned char* ldsb = &lds[0][0];
  int tid = threadIdx.x;
  int wv = tid >> 6, lane = tid & 63;
  int n = lane & 15, g = lane >> 4;

  // XCD-aware bijective swizzle (1024 % 8 == 0)
  int bid = blockIdx.x;
  int swz = (bid & 7) * 128 + (bid >> 3);
  int bi = swz >> 5, qt = swz & 31;

  size_t Rq = (size_t)bi * 2048 + qt * 64 + wv * 16;

  const unsigned char* Kg = (const unsigned char*)KF + (size_t)bi * 131072;
  const unsigned char* Vg = (const unsigned char*)VF + (size_t)bi * 131072;

  // staging: wave wv covers 2KB of the 8KB (K|V) tile; 2 x 16B per lane
  const unsigned char* sgp = (wv < 2 ? Kg : Vg) + (wv & 1) * 2048 + lane * 16;
  unsigned char* ldsw = ldsb + (wv < 2 ? 0 : 4096) + (wv & 1) * 2048 + lane * 16;

  bf16x8 qf = *(const bf16x8*)(Qb + (Rq + n) * 32 + g * 8);

  f32x4 oA0 = (f32x4)0.0f, oA1 = (f32x4)0.0f; // kt 0,1 x eblk 0,1
  f32x4 oB0 = (f32x4)0.0f, oB1 = (f32x4)0.0f; // kt 2,3 x eblk 0,1
  float lsum = 0.0f;

  bf16x8 kr0, kr1;

  // prologue: stage tile 0 into buf0
  kr0 = *(const bf16x8*)(sgp);
  kr1 = *(const bf16x8*)(sgp + 1024);
  sgp += 4096;
  *(bf16x8*)(ldsw) = kr0;
  *(bf16x8*)(ldsw + 1024) = kr1;
  __syncthreads();

  for (int t = 0; t < 32; ++t) {
    int buf = t & 1;
    if (t < 31) { // issue next tile's loads early (one compute phase of cover)
      kr0 = *(const bf16x8*)(sgp);
      kr1 = *(const bf16x8*)(sgp + 1024);
      sgp += 4096;
    }
    const unsigned char* Lp = ldsb + buf * 8192;
    bf16x8 kf0 = *(const bf16x8*)(Lp + lane * 16);
    bf16x8 kf1 = *(const bf16x8*)(Lp + lane * 16 + 1024);
    bf16x8 kf2 = *(const bf16x8*)(Lp + lane * 16 + 2048);
    bf16x8 kf3 = *(const bf16x8*)(Lp + lane * 16 + 3072);
    u32x2 vf0 = *(const u32x2*)(Lp + 4096 + lane * 8);
    u32x2 vf1 = *(const u32x2*)(Lp + 4096 + lane * 8 + 512);
    u32x2 vf2 = *(const u32x2*)(Lp + 4096 + lane * 8 + 1024);
    u32x2 vf3 = *(const u32x2*)(Lp + 4096 + lane * 8 + 1536);
    u32x2 vf4 = *(const u32x2*)(Lp + 4096 + lane * 8 + 2048);
    u32x2 vf5 = *(const u32x2*)(Lp + 4096 + lane * 8 + 2560);
    u32x2 vf6 = *(const u32x2*)(Lp + 4096 + lane * 8 + 3072);
    u32x2 vf7 = *(const u32x2*)(Lp + 4096 + lane * 8 + 3584);
    f32x4 s0 = __builtin_amdgcn_mfma_f32_16x16x32_bf16(kf0, qf, (f32x4)0.0f, 0, 0, 0);
    f32x4 s1 = __builtin_amdgcn_mfma_f32_16x16x32_bf16(kf1, qf, (f32x4)0.0f, 0, 0, 0);
    f32x4 s2 = __builtin_amdgcn_mfma_f32_16x16x32_bf16(kf2, qf, (f32x4)0.0f, 0, 0, 0);
    f32x4 s3 = __builtin_amdgcn_mfma_f32_16x16x32_bf16(kf3, qf, (f32x4)0.0f, 0, 0, 0);
    unsigned pk[8];
    SMAX(s0, 0) SMAX(s1, 2) SMAX(s2, 4) SMAX(s3, 6)
    PVKT(0, vf0, vf4, oA0, oA1) PVKT(1, vf1, vf5, oA0, oA1)
    PVKT(2, vf2, vf6, oB0, oB1) PVKT(3, vf3, vf7, oB0, oB1)
    __syncthreads();              // all waves done reading buf
    if (t < 31) {
      unsigned char* Wp = ldsw + (buf ^ 1) * 8192;
      *(bf16x8*)(Wp) = kr0;       // compiler inserts vmcnt wait before ds_write
      *(bf16x8*)(Wp + 1024) = kr1;
      __syncthreads();            // stage of tile t+1 visible to all
    }
  }

  // full row-sum for q-row n: partials live in lanes n, n+16, n+32, n+48
  lsum += __shfl_xor(lsum, 16);
  lsum += __shfl_xor(lsum, 32);
  float inv = 1.0f / lsum;

  // O: lane(n,g) reg r holds O[q=Rq+n][e = eblk*16 + g*4 + r]
  f32x4 r0 = (oA0 + oB0) * inv;
  f32x4 r1 = (oA1 + oB1) * inv;
  float* ob = out + (Rq + n) * 32 + g * 4;
  *(f32x4*)(ob)      = r0;
  *(f32x4*)(ob + 16) = r1;
}

extern "C" void kernel_launch(void* const* d_in, const int* in_sizes, int n_in,
                              void* d_out, int out_size, void* d_ws, size_t ws_size,
                              hipStream_t stream) {
  const float* x = (const float*)d_in[0];
  const float* w = (const float*)d_in[1];
  float* out = (float*)d_out;

  unsigned short* KF = (unsigned short*)d_ws;          // 4MB, fragment-order K
  unsigned short* VF = KF + (size_t)65536 * 32;        // 4MB, fragment-order V
  unsigned short* Qb = VF + (size_t)65536 * 32;        // 4MB

  qkv_kernel<<<1536, 256, 0, stream>>>(x, w, Qb, KF, VF);
  attn_kernel<<<1024, 256, 0, stream>>>(Qb, KF, VF, out);
}

// Round 16
// 48.054 us; speedup vs baseline: 1.0303x; 1.0303x over previous
//
#include <hip/hip_runtime.h>
#include <hip/hip_bf16.h>

// Self-attention: b=32, s=2048, d=32, f32 in/out.
// qkv (split, 3-head grid): x tile staged coalesced (R15); Q pre-scaled;
//   K fragment-order (KF); V fragment-order PAIRED (VP): kt-pair chunks
//   adjacent so attn reads V as ds_read_b128 (4 reads vs 8 b64).
// attn: R12/R15 sync template BYTE-IDENTICAL (double-buffered LDS reg-staging,
//   compute -> barrier -> ds_write -> barrier); only V read addressing changed.
// ws: KF 4MB | VP 4MB | Qb 4MB.

typedef __attribute__((ext_vector_type(8))) short bf16x8;
typedef __attribute__((ext_vector_type(4))) short bf16x4;
typedef __attribute__((ext_vector_type(4))) float f32x4;
typedef __attribute__((ext_vector_type(2))) unsigned int u32x2;
typedef __attribute__((ext_vector_type(4))) unsigned int u32x4;

#if __has_builtin(__builtin_amdgcn_mfma_f32_16x16x16bf16_1k)
#define MFMA_PV(a, b, c) __builtin_amdgcn_mfma_f32_16x16x16bf16_1k(a, b, c, 0, 0, 0)
#elif defined(__HIP_DEVICE_COMPILE__)
#error "no 16x16x16 bf16 mfma builtin on device"
#else
#define MFMA_PV(a, b, c) (c) /* host stub, never executed */
#endif

__device__ __forceinline__ unsigned cvt_pk_bf16(float lo, float hi) {
  unsigned r;
  asm("v_cvt_pk_bf16_f32 %0, %1, %2" : "=v"(r) : "v"(lo), "v"(hi));
  return r;
}
__device__ __forceinline__ bf16x4 as_bf16x4(u32x2 u) {
  union { u32x2 a; bf16x4 b; } c; c.a = u; return c.b;
}

// ---------------- QKV projection ----------------
// grid 1536 = 3 heads x 512 blocks; 256 thr; half = tid>>7, 128 rows/block
__global__ __launch_bounds__(256) void qkv_kernel(
    const float* __restrict__ x, const float* __restrict__ w,
    unsigned short* __restrict__ Qb, unsigned short* __restrict__ KF,
    unsigned short* __restrict__ VP) {
  __shared__ float Wlds[1024];
  __shared__ float xs[4608];                       // 128 rows x 36 floats (pad +4)
  __shared__ __align__(16) unsigned char RP[8192]; // repack buffer (h==1 / h==2)
  int tid = threadIdx.x;
  int h = blockIdx.x >> 9;
  int rb = blockIdx.x & 511;

  // coalesced x tile stage (R15-verified)
  const float* xg = x + (size_t)(rb * 128) * 32;
#pragma unroll
  for (int k2 = 0; k2 < 4; ++k2) {
    int fi = k2 * 1024 + tid * 4;
    f32x4 v = *(const f32x4*)(xg + fi);
    *(f32x4*)(&xs[(fi >> 5) * 36 + (fi & 31)]) = v;
  }
#pragma unroll
  for (int i = 0; i < 4; ++i) Wlds[i * 256 + tid] = w[h * 1024 + i * 256 + tid];
  __syncthreads();

  int half = tid >> 7;
  int row = rb * 128 + (tid & 127);
  const float* xr = &xs[(tid & 127) * 36];
  f32x4 xv[8];
#pragma unroll
  for (int j = 0; j < 8; ++j) xv[j] = *(const f32x4*)(xr + j * 4);

  f32x4 acc[4];
#pragma unroll
  for (int j = 0; j < 4; ++j) acc[j] = (f32x4)0.0f;
#pragma unroll
  for (int d = 0; d < 32; ++d) {
    float xd = xv[d >> 2][d & 3];
    const f32x4* wr = (const f32x4*)&Wlds[d * 32 + half * 16];
#pragma unroll
    for (int j = 0; j < 4; ++j) acc[j] += xd * wr[j];
  }

  const float alpha = 1.4426950408889634f * 0.17677669529663687f; // log2e/sqrt(32)
  int L = tid & 127;

  if (h == 0) {
    u32x4 o4[2];
#pragma unroll
    for (int q = 0; q < 2; ++q)
#pragma unroll
      for (int c = 0; c < 4; ++c) {
        int e = q * 8 + c * 2;
        o4[q][c] = cvt_pk_bf16(acc[e >> 2][e & 3] * alpha, acc[(e + 1) >> 2][(e + 1) & 3] * alpha);
      }
    u32x4* dst = (u32x4*)(Qb + (size_t)row * 32 + half * 16);
    dst[0] = o4[0];
    dst[1] = o4[1];
  } else if (h == 1) {
    // K fragment-order: tile byte = kt*1024 + g*256 + n*16 (+ kcl*4096)  [R12-verified]
    int kcl = L >> 6, kt = (L >> 4) & 3, n = L & 15;
    u32x4 o4[2];
#pragma unroll
    for (int q = 0; q < 2; ++q)
#pragma unroll
      for (int c = 0; c < 4; ++c) {
        int e = q * 8 + c * 2;
        o4[q][c] = cvt_pk_bf16(acc[e >> 2][e & 3], acc[(e + 1) >> 2][(e + 1) & 3]);
      }
    *(u32x4*)(RP + kcl * 4096 + kt * 1024 + (2 * half + 0) * 256 + n * 16) = o4[0];
    *(u32x4*)(RP + kcl * 4096 + kt * 1024 + (2 * half + 1) * 256 + n * 16) = o4[1];
    __syncthreads();
    char* dst = (char*)KF + (size_t)rb * 8192;
#pragma unroll
    for (int m = 0; m < 4; ++m)
      *(u32x2*)(dst + tid * 8 + m * 2048) = *(const u32x2*)(RP + tid * 8 + m * 2048);
  } else {
    // V fragment-order PAIRED repack (kt-pair chunks adjacent).
    // chunk(kt,e,g,n) now at byte e*2048 + (kt>>1)*1024 + g*256 + n*16 + (kt&1)*8
    // (same chunk CONTENTS as verified layout; only addresses permuted;
    //  bit-fields disjoint -> bijective, max short index 4095)
    unsigned short* VFlds = (unsigned short*)RP;
    int kcl = L >> 6, kt = (L >> 4) & 3, g = (L >> 2) & 3, i = L & 3;
    int base = kcl * 2048 + half * 1024 + (kt >> 1) * 512 + g * 128 + (kt & 1) * 4 + i;
#pragma unroll
    for (int nn = 0; nn < 16; ++nn) {
      unsigned r = cvt_pk_bf16(acc[nn >> 2][nn & 3], acc[nn >> 2][nn & 3]);
      VFlds[base + nn * 8] = (unsigned short)(r & 0xffffu);
    }
    __syncthreads();
    char* dst = (char*)VP + (size_t)rb * 8192;
#pragma unroll
    for (int m = 0; m < 4; ++m)
      *(u32x2*)(dst + tid * 8 + m * 2048) = *(const u32x2*)(RP + tid * 8 + m * 2048);
  }
}

// ---------------- Flash attention (R12/R15 template; V reads now b128) ----------------
#define SMAX(SF, I2) {                                           \
    float p0 = __builtin_amdgcn_exp2f(SF[0]);                    \
    float p1 = __builtin_amdgcn_exp2f(SF[1]);                    \
    float p2 = __builtin_amdgcn_exp2f(SF[2]);                    \
    float p3 = __builtin_amdgcn_exp2f(SF[3]);                    \
    lsum += (p0 + p1) + (p2 + p3);                               \
    pk[I2] = cvt_pk_bf16(p0, p1);                                \
    pk[I2 + 1] = cvt_pk_bf16(p2, p3); }

#define PVKT(KT, V0, V1, ACC0, ACC1) {                           \
    u32x2 bw; bw[0] = pk[2 * KT]; bw[1] = pk[2 * KT + 1];        \
    bf16x4 bb = as_bf16x4(bw);                                   \
    ACC0 = MFMA_PV(as_bf16x4(V0), bb, ACC0);                     \
    ACC1 = MFMA_PV(as_bf16x4(V1), bb, ACC1); }

// grid: 1024 blocks (32 b x 32 q-tiles of 64), 256 threads (4 waves x 16 q-rows)
__global__ __launch_bounds__(256, 4) void attn_kernel(
    const unsigned short* __restrict__ Qb, const unsigned short* __restrict__ KF,
    const unsigned short* __restrict__ VP, float* __restrict__ out) {
  __shared__ __align__(16) unsigned char lds[2][8192]; // 2 x (K 4KB | V 4KB)
  unsigned char* ldsb = &lds[0][0];
  int tid = threadIdx.x;
  int wv = tid >> 6, lane = tid & 63;
  int n = lane & 15, g = lane >> 4;

  // XCD-aware bijective swizzle (1024 % 8 == 0)
  int bid = blockIdx.x;
  int swz = (bid & 7) * 128 + (bid >> 3);
  int bi = swz >> 5, qt = swz & 31;

  size_t Rq = (size_t)bi * 2048 + qt * 64 + wv * 16;

  const unsigned char* Kg = (const unsigned char*)KF + (size_t)bi * 131072;
  const unsigned char* Vg = (const unsigned char*)VP + (size_t)bi * 131072;

  // staging: wave wv covers 2KB of the 8KB (K|V) tile; 2 x 16B per lane
  const unsigned char* sgp = (wv < 2 ? Kg : Vg) + (wv & 1) * 2048 + lane * 16;
  unsigned char* ldsw = ldsb + (wv < 2 ? 0 : 4096) + (wv & 1) * 2048 + lane * 16;

  bf16x8 qf = *(const bf16x8*)(Qb + (Rq + n) * 32 + g * 8);

  f32x4 oA0 = (f32x4)0.0f, oA1 = (f32x4)0.0f; // kt 0,1 x eblk 0,1
  f32x4 oB0 = (f32x4)0.0f, oB1 = (f32x4)0.0f; // kt 2,3 x eblk 0,1
  float lsum = 0.0f;

  bf16x8 kr0, kr1;

  // prologue: stage tile 0 into buf0
  kr0 = *(const bf16x8*)(sgp);
  kr1 = *(const bf16x8*)(sgp + 1024);
  sgp += 4096;
  *(bf16x8*)(ldsw) = kr0;
  *(bf16x8*)(ldsw + 1024) = kr1;
  __syncthreads();

  for (int t = 0; t < 32; ++t) {
    int buf = t & 1;
    if (t < 31) { // issue next tile's loads early (one compute phase of cover)
      kr0 = *(const bf16x8*)(sgp);
      kr1 = *(const bf16x8*)(sgp + 1024);
      sgp += 4096;
    }
    const unsigned char* Lp = ldsb + buf * 8192;
    bf16x8 kf0 = *(const bf16x8*)(Lp + lane * 16);
    bf16x8 kf1 = *(const bf16x8*)(Lp + lane * 16 + 1024);
    bf16x8 kf2 = *(const bf16x8*)(Lp + lane * 16 + 2048);
    bf16x8 kf3 = *(const bf16x8*)(Lp + lane * 16 + 3072);
    // V: 4 x b128, each = (kt=2p | kt=2p+1) pair for eblk e
    u32x4 w00 = *(const u32x4*)(Lp + 4096 + lane * 16);          // e0, kt0|kt1
    u32x4 w01 = *(const u32x4*)(Lp + 4096 + lane * 16 + 1024);   // e0, kt2|kt3
    u32x4 w10 = *(const u32x4*)(Lp + 4096 + lane * 16 + 2048);   // e1, kt0|kt1
    u32x4 w11 = *(const u32x4*)(Lp + 4096 + lane * 16 + 3072);   // e1, kt2|kt3
    u32x2 vf0; vf0[0] = w00[0]; vf0[1] = w00[1];
    u32x2 vf1; vf1[0] = w00[2]; vf1[1] = w00[3];
    u32x2 vf2; vf2[0] = w01[0]; vf2[1] = w01[1];
    u32x2 vf3; vf3[0] = w01[2]; vf3[1] = w01[3];
    u32x2 vf4; vf4[0] = w10[0]; vf4[1] = w10[1];
    u32x2 vf5; vf5[0] = w10[2]; vf5[1] = w10[3];
    u32x2 vf6; vf6[0] = w11[0]; vf6[1] = w11[1];
    u32x2 vf7; vf7[0] = w11[2]; vf7[1] = w11[3];
    f32x4 s0 = __builtin_amdgcn_mfma_f32_16x16x32_bf16(kf0, qf, (f32x4)0.0f, 0, 0, 0);
    f32x4 s1 = __builtin_amdgcn_mfma_f32_16x16x32_bf16(kf1, qf, (f32x4)0.0f, 0, 0, 0);
    f32x4 s2 = __builtin_amdgcn_mfma_f32_16x16x32_bf16(kf2, qf, (f32x4)0.0f, 0, 0, 0);
    f32x4 s3 = __builtin_amdgcn_mfma_f32_16x16x32_bf16(kf3, qf, (f32x4)0.0f, 0, 0, 0);
    unsigned pk[8];
    SMAX(s0, 0) SMAX(s1, 2) SMAX(s2, 4) SMAX(s3, 6)
    PVKT(0, vf0, vf4, oA0, oA1) PVKT(1, vf1, vf5, oA0, oA1)
    PVKT(2, vf2, vf6, oB0, oB1) PVKT(3, vf3, vf7, oB0, oB1)
    __syncthreads();              // all waves done reading buf
    if (t < 31) {
      unsigned char* Wp = ldsw + (buf ^ 1) * 8192;
      *(bf16x8*)(Wp) = kr0;       // compiler inserts vmcnt wait before ds_write
      *(bf16x8*)(Wp + 1024) = kr1;
      __syncthreads();            // stage of tile t+1 visible to all
    }
  }

  // full row-sum for q-row n: partials live in lanes n, n+16, n+32, n+48
  lsum += __shfl_xor(lsum, 16);
  lsum += __shfl_xor(lsum, 32);
  float inv = 1.0f / lsum;

  // O: lane(n,g) reg r holds O[q=Rq+n][e = eblk*16 + g*4 + r]
  f32x4 r0 = (oA0 + oB0) * inv;
  f32x4 r1 = (oA1 + oB1) * inv;
  float* ob = out + (Rq + n) * 32 + g * 4;
  *(f32x4*)(ob)      = r0;
  *(f32x4*)(ob + 16) = r1;
}

extern "C" void kernel_launch(void* const* d_in, const int* in_sizes, int n_in,
                              void* d_out, int out_size, void* d_ws, size_t ws_size,
                              hipStream_t stream) {
  const float* x = (const float*)d_in[0];
  const float* w = (const float*)d_in[1];
  float* out = (float*)d_out;

  unsigned short* KF = (unsigned short*)d_ws;          // 4MB, fragment-order K
  unsigned short* VP = KF + (size_t)65536 * 32;        // 4MB, paired fragment-order V
  unsigned short* Qb = VP + (size_t)65536 * 32;        // 4MB

  qkv_kernel<<<1536, 256, 0, stream>>>(x, w, Qb, KF, VP);
  attn_kernel<<<1024, 256, 0, stream>>>(Qb, KF, VP, out);
}